// Round 1
// baseline (805.652 us; speedup 1.0000x reference)
//
#include <hip/hip_runtime.h>

typedef __attribute__((ext_vector_type(8))) short bf16x8;
typedef __attribute__((ext_vector_type(8))) unsigned short u16x8;
typedef __attribute__((ext_vector_type(4))) float f32x4;

#define B_ 2
#define N_ 16384
#define DIM_ 256
#define H_ 8
#define DH_ 32
#define GS_ 128
#define NG_ 128
#define M_ 64
#define SCALE 0.17677669529663687f   // 1/sqrt(32)

#define KW 40    // padded row length (elems) for 32-wide bf16 tiles: 80B stride, 16B aligned, ~2-way banks
#define FW 328   // fused buffer row: 256 window + 64 global + 8 pad -> 656B stride (41*16)
#define XW 264   // 256 + 8 pad -> 528B stride (33*16)

__device__ __forceinline__ unsigned short f2bf(float x) {
  union { float f; unsigned u; } v; v.f = x;
  unsigned r = v.u + 0x7fffu + ((v.u >> 16) & 1u);
  return (unsigned short)(r >> 16);
}

// ---------------- K0a: transpose W (f32 [256][256]) -> WT (bf16 [256][256]) ----------------
__global__ void k0_transpose(const float* __restrict__ W0, const float* __restrict__ W1,
                             const float* __restrict__ W2, const float* __restrict__ W3,
                             unsigned short* __restrict__ WT) {
  __shared__ float t[32][33];
  const float* W = (blockIdx.z == 0) ? W0 : (blockIdx.z == 1) ? W1 : (blockIdx.z == 2) ? W2 : W3;
  unsigned short* D = WT + (size_t)blockIdx.z * 65536;
  int tx = threadIdx.x & 31, ty = threadIdx.x >> 5;
  int r0 = blockIdx.y * 32, c0 = blockIdx.x * 32;
#pragma unroll
  for (int k = 0; k < 4; ++k)
    t[ty + 8 * k][tx] = W[(size_t)(r0 + ty + 8 * k) * 256 + c0 + tx];
  __syncthreads();
#pragma unroll
  for (int k = 0; k < 4; ++k)
    D[(size_t)(c0 + ty + 8 * k) * 256 + r0 + tx] = f2bf(t[tx][ty + 8 * k]);
}

// ---------------- K0b: k_global -> bf16 copy; v_global -> bf16 transposed [h][d][m] --------
__global__ void k0_kgvg(const float* __restrict__ kgf, const float* __restrict__ vgf,
                        unsigned short* __restrict__ kgb, unsigned short* __restrict__ vgt) {
  int i = blockIdx.x * 256 + threadIdx.x;
  if (i < H_ * M_ * DH_) {
    kgb[i] = f2bf(kgf[i]);
    int hh = i >> 11, rem = i & 2047, d = rem >> 6, mm = rem & 63;
    vgt[i] = f2bf(vgf[((size_t)hh * M_ + mm) * DH_ + d]);
  }
}

// ---------------- K1: gathered QKV projection -> qg/kg/vg bf16 [B][H][N][32] ----------------
__global__ __launch_bounds__(512) void k1_qkv(const float* __restrict__ x, const int* __restrict__ idx,
                                              const unsigned short* __restrict__ WT,
                                              unsigned short* __restrict__ qg,
                                              unsigned short* __restrict__ kg,
                                              unsigned short* __restrict__ vg) {
  __shared__ __attribute__((aligned(16))) unsigned short Xs[128 * XW];
  const int tid = threadIdx.x;
  const int brow0 = blockIdx.x * 128;  // gathered global row base (b*N + n)
  const int b = brow0 >> 14;
  {
    int r = tid >> 2, part = tid & 3;
    int src = idx[brow0 + r];
    const float* xp = x + ((size_t)b * N_ + src) * DIM_ + part * 64;
    unsigned short* dp = &Xs[r * XW + part * 64];
#pragma unroll
    for (int i = 0; i < 8; ++i) {
      float4 v0 = ((const float4*)xp)[2 * i];
      float4 v1 = ((const float4*)xp)[2 * i + 1];
      u16x8 o;
      o[0] = f2bf(v0.x); o[1] = f2bf(v0.y); o[2] = f2bf(v0.z); o[3] = f2bf(v0.w);
      o[4] = f2bf(v1.x); o[5] = f2bf(v1.y); o[6] = f2bf(v1.z); o[7] = f2bf(v1.w);
      *(u16x8*)(dp + i * 8) = o;
    }
  }
  __syncthreads();
  const int lane = tid & 63, wid = tid >> 6;
  const int l15 = lane & 15, l4 = lane >> 4;
  const int qr0 = wid * 16;
  bf16x8 a[8];
#pragma unroll
  for (int ks = 0; ks < 8; ++ks)
    a[ks] = *(const bf16x8*)&Xs[(qr0 + l15) * XW + ks * 32 + l4 * 8];
#pragma unroll
  for (int w = 0; w < 3; ++w) {
    const unsigned short* WTm = WT + w * 65536;
    unsigned short* dst = (w == 0) ? qg : (w == 1) ? kg : vg;
    for (int ct = 0; ct < 16; ++ct) {
      f32x4 acc = {0.f, 0.f, 0.f, 0.f};
#pragma unroll
      for (int ks = 0; ks < 8; ++ks) {
        bf16x8 bfr = *(const bf16x8*)&WTm[(ct * 16 + l15) * 256 + ks * 32 + l4 * 8];
        acc = __builtin_amdgcn_mfma_f32_16x16x32_bf16(a[ks], bfr, acc, 0, 0, 0);
      }
      int col = ct * 16 + l15, hh = col >> 5, cc = col & 31;
#pragma unroll
      for (int r = 0; r < 4; ++r) {
        int grow = brow0 + qr0 + l4 * 4 + r;
        int n = grow & (N_ - 1);
        dst[(((size_t)((grow >> 14) * H_ + hh)) * N_ + n) * DH_ + cc] = f2bf(acc[r]);
      }
    }
  }
}

// ---------------- K2: fused windowed + global attention per (b,g,h) ----------------
__global__ __launch_bounds__(512) void k2_attn(
    const unsigned short* __restrict__ qg, const unsigned short* __restrict__ kgv,
    const unsigned short* __restrict__ vgv, const unsigned short* __restrict__ kglob,
    const unsigned short* __restrict__ vgt, const int* __restrict__ sbi,
    const float* __restrict__ prev, float* __restrict__ fusedOut,
    unsigned short* __restrict__ outPre) {
  __shared__ __attribute__((aligned(16))) unsigned short Qs[128 * KW];
  __shared__ __attribute__((aligned(16))) unsigned short Ks[256 * KW];
  __shared__ __attribute__((aligned(16))) unsigned short Vts[32 * FW];   // [d][320] : window V^T | vg^T
  __shared__ __attribute__((aligned(16))) unsigned short Kgs[64 * KW];
  __shared__ int bq[128];
  __shared__ int bk[256];
  __shared__ __attribute__((aligned(16))) unsigned short Fs[128 * FW];   // fused probs | global probs (bf16)

  const int tid = threadIdx.x;
  const int h = blockIdx.x & 7;
  const int g = (blockIdx.x >> 3) & 127;
  const int b = blockIdx.x >> 10;
  const int n0 = g * GS_;
  const size_t headBase = ((size_t)b * H_ + h) * (size_t)N_ * DH_;

  {  // Q: 128 rows x 4 chunks of 8 bf16
    int r = tid >> 2, q = tid & 3;
    *(u16x8*)&Qs[r * KW + q * 8] = *(const u16x8*)&qg[headBase + (size_t)(n0 + r) * DH_ + q * 8];
  }
#pragma unroll
  for (int it = 0; it < 2; ++it) {  // K window: 256 rows x 4 chunks
    int slot = tid + it * 512;
    int w = slot >> 2, q = slot & 3;
    int srcn = (w < 128 || g < NG_ - 1) ? (n0 + w) : (N_ - 1 - (w - 128));
    *(u16x8*)&Ks[w * KW + q * 8] = *(const u16x8*)&kgv[headBase + (size_t)srcn * DH_ + q * 8];
  }
  {  // V window, transposed into Vts[d][w]
    int w = tid >> 1, hh = tid & 1;
    int srcn = (w < 128 || g < NG_ - 1) ? (n0 + w) : (N_ - 1 - (w - 128));
    const unsigned short* src = &vgv[headBase + (size_t)srcn * DH_ + hh * 16];
    u16x8 v0 = *(const u16x8*)src;
    u16x8 v1 = *(const u16x8*)(src + 8);
#pragma unroll
    for (int j = 0; j < 8; ++j) {
      Vts[(hh * 16 + j) * FW + w] = v0[j];
      Vts[(hh * 16 + 8 + j) * FW + w] = v1[j];
    }
  }
  if (tid < 128) {  // v_global^T into Vts cols 256..319
    int d = tid >> 2, q = tid & 3;
    const unsigned short* src = &vgt[((size_t)h * DH_ + d) * M_ + q * 16];
    *(u16x8*)&Vts[d * FW + 256 + q * 16] = *(const u16x8*)src;
    *(u16x8*)&Vts[d * FW + 256 + q * 16 + 8] = *(const u16x8*)(src + 8);
  }
  if (tid < 256) {  // k_global rows
    int m = tid >> 2, q = tid & 3;
    *(u16x8*)&Kgs[m * KW + q * 8] = *(const u16x8*)&kglob[((size_t)h * M_ + m) * DH_ + q * 8];
  }
  if (tid < 128) bq[tid] = sbi[b * N_ + n0 + tid];
  if (tid >= 256) {
    int w = tid - 256;
    int srcn = (w < 128 || g < NG_ - 1) ? (n0 + w) : (N_ - 1 - (w - 128));
    bk[w] = sbi[b * N_ + srcn];
  }
  __syncthreads();

  const int lane = tid & 63, wid = tid >> 6;
  const int l15 = lane & 15, l4 = lane >> 4;
  const int qr0 = wid * 16;

  bf16x8 qa = *(const bf16x8*)&Qs[(qr0 + l15) * KW + l4 * 8];

  f32x4 c[16];
#pragma unroll
  for (int ct = 0; ct < 16; ++ct) {
    bf16x8 kb = *(const bf16x8*)&Ks[(ct * 16 + l15) * KW + l4 * 8];
    f32x4 z = {0.f, 0.f, 0.f, 0.f};
    c[ct] = __builtin_amdgcn_mfma_f32_16x16x32_bf16(qa, kb, z, 0, 0, 0);
  }

  int bkv[16];
#pragma unroll
  for (int ct = 0; ct < 16; ++ct) bkv[ct] = bk[ct * 16 + l15];
  int myq[4];
#pragma unroll
  for (int r = 0; r < 4; ++r) myq[r] = bq[qr0 + l4 * 4 + r];

  float mx[4] = {-1e30f, -1e30f, -1e30f, -1e30f};
#pragma unroll
  for (int ct = 0; ct < 16; ++ct)
#pragma unroll
    for (int r = 0; r < 4; ++r) {
      float v = c[ct][r] * SCALE;
      c[ct][r] = v;
      if (bkv[ct] == myq[r]) mx[r] = fmaxf(mx[r], v);
    }
#pragma unroll
  for (int r = 0; r < 4; ++r) {
    mx[r] = fmaxf(mx[r], __shfl_xor(mx[r], 1));
    mx[r] = fmaxf(mx[r], __shfl_xor(mx[r], 2));
    mx[r] = fmaxf(mx[r], __shfl_xor(mx[r], 4));
    mx[r] = fmaxf(mx[r], __shfl_xor(mx[r], 8));
  }
  float sm[4] = {0.f, 0.f, 0.f, 0.f};
#pragma unroll
  for (int ct = 0; ct < 16; ++ct)
#pragma unroll
    for (int r = 0; r < 4; ++r) {
      float p = (bkv[ct] == myq[r]) ? __expf(c[ct][r] - mx[r]) : 0.f;
      c[ct][r] = p;
      sm[r] += p;
    }
#pragma unroll
  for (int r = 0; r < 4; ++r) {
    sm[r] += __shfl_xor(sm[r], 1);
    sm[r] += __shfl_xor(sm[r], 2);
    sm[r] += __shfl_xor(sm[r], 4);
    sm[r] += __shfl_xor(sm[r], 8);
  }
  float inv[4];
#pragma unroll
  for (int r = 0; r < 4; ++r) inv[r] = 1.f / sm[r];

  const size_t pbase = ((((size_t)b * NG_ + g) * H_ + h) * GS_) * (size_t)(2 * GS_);
  float fs[4] = {0.f, 0.f, 0.f, 0.f};
#pragma unroll
  for (int ct = 0; ct < 16; ++ct)
#pragma unroll
    for (int r = 0; r < 4; ++r) {
      int row = qr0 + l4 * 4 + r;
      float pr = prev[pbase + (size_t)row * 256 + ct * 16 + l15];
      float f = (bkv[ct] == myq[r]) ? (0.5f * pr + 0.5f * c[ct][r] * inv[r]) : 0.f;
      c[ct][r] = f;
      fs[r] += f;
    }
#pragma unroll
  for (int r = 0; r < 4; ++r) {
    fs[r] += __shfl_xor(fs[r], 1);
    fs[r] += __shfl_xor(fs[r], 2);
    fs[r] += __shfl_xor(fs[r], 4);
    fs[r] += __shfl_xor(fs[r], 8);
  }
  float fn[4];
#pragma unroll
  for (int r = 0; r < 4; ++r) fn[r] = 1.f / (fs[r] + 1e-9f);
#pragma unroll
  for (int ct = 0; ct < 16; ++ct)
#pragma unroll
    for (int r = 0; r < 4; ++r) {
      int row = qr0 + l4 * 4 + r;
      float f = c[ct][r] * fn[r];
      fusedOut[pbase + (size_t)row * 256 + ct * 16 + l15] = f;
      Fs[row * FW + ct * 16 + l15] = f2bf(f);
    }

  // global attention: s2 = Q * kg^T, softmax, probs -> Fs cols 256..319
  f32x4 c2[4];
#pragma unroll
  for (int ct = 0; ct < 4; ++ct) {
    bf16x8 kb = *(const bf16x8*)&Kgs[(ct * 16 + l15) * KW + l4 * 8];
    f32x4 z = {0.f, 0.f, 0.f, 0.f};
    c2[ct] = __builtin_amdgcn_mfma_f32_16x16x32_bf16(qa, kb, z, 0, 0, 0);
  }
  float m2[4] = {-1e30f, -1e30f, -1e30f, -1e30f};
#pragma unroll
  for (int ct = 0; ct < 4; ++ct)
#pragma unroll
    for (int r = 0; r < 4; ++r) {
      float v = c2[ct][r] * SCALE;
      c2[ct][r] = v;
      m2[r] = fmaxf(m2[r], v);
    }
#pragma unroll
  for (int r = 0; r < 4; ++r) {
    m2[r] = fmaxf(m2[r], __shfl_xor(m2[r], 1));
    m2[r] = fmaxf(m2[r], __shfl_xor(m2[r], 2));
    m2[r] = fmaxf(m2[r], __shfl_xor(m2[r], 4));
    m2[r] = fmaxf(m2[r], __shfl_xor(m2[r], 8));
  }
  float s2[4] = {0.f, 0.f, 0.f, 0.f};
#pragma unroll
  for (int ct = 0; ct < 4; ++ct)
#pragma unroll
    for (int r = 0; r < 4; ++r) {
      float p = __expf(c2[ct][r] - m2[r]);
      c2[ct][r] = p;
      s2[r] += p;
    }
#pragma unroll
  for (int r = 0; r < 4; ++r) {
    s2[r] += __shfl_xor(s2[r], 1);
    s2[r] += __shfl_xor(s2[r], 2);
    s2[r] += __shfl_xor(s2[r], 4);
    s2[r] += __shfl_xor(s2[r], 8);
  }
#pragma unroll
  for (int ct = 0; ct < 4; ++ct)
#pragma unroll
    for (int r = 0; r < 4; ++r) {
      int row = qr0 + l4 * 4 + r;
      Fs[row * FW + 256 + ct * 16 + l15] = f2bf(c2[ct][r] / s2[r]);
    }

  __syncthreads();  // make per-wave Fs writes visible across lanes

  // PV over 320 cols: out = [fused|p2] @ [Vwin ; vg]
  f32x4 acc0 = {0.f, 0.f, 0.f, 0.f}, acc1 = {0.f, 0.f, 0.f, 0.f};
#pragma unroll
  for (int kt = 0; kt < 10; ++kt) {
    bf16x8 af = *(const bf16x8*)&Fs[(qr0 + l15) * FW + kt * 32 + l4 * 8];
    bf16x8 b0 = *(const bf16x8*)&Vts[l15 * FW + kt * 32 + l4 * 8];
    bf16x8 b1 = *(const bf16x8*)&Vts[(16 + l15) * FW + kt * 32 + l4 * 8];
    acc0 = __builtin_amdgcn_mfma_f32_16x16x32_bf16(af, b0, acc0, 0, 0, 0);
    acc1 = __builtin_amdgcn_mfma_f32_16x16x32_bf16(af, b1, acc1, 0, 0, 0);
  }
#pragma unroll
  for (int r = 0; r < 4; ++r) {
    int row = qr0 + l4 * 4 + r;
    size_t orow = ((size_t)b * N_ + n0 + row) * DIM_ + h * DH_;
    outPre[orow + l15] = f2bf(acc0[r]);
    outPre[orow + 16 + l15] = f2bf(acc1[r]);
  }
}

// ---------------- K3: out[b, idx[n], :] = outPre[b, n, :] @ Wproj ----------------
__global__ __launch_bounds__(512) void k3_proj(const unsigned short* __restrict__ outPre,
                                               const unsigned short* __restrict__ WpT,
                                               const int* __restrict__ idx,
                                               float* __restrict__ out) {
  __shared__ __attribute__((aligned(16))) unsigned short As[128 * XW];
  const int tid = threadIdx.x;
  const int brow0 = blockIdx.x * 128;
  {
    int r = tid >> 2, part = tid & 3;
    const unsigned short* sp = &outPre[(size_t)(brow0 + r) * 256 + part * 64];
    unsigned short* dp = &As[r * XW + part * 64];
#pragma unroll
    for (int i = 0; i < 8; ++i)
      *(u16x8*)(dp + i * 8) = *(const u16x8*)(sp + i * 8);
  }
  __syncthreads();
  const int lane = tid & 63, wid = tid >> 6;
  const int l15 = lane & 15, l4 = lane >> 4;
  const int qr0 = wid * 16;
  bf16x8 a[8];
#pragma unroll
  for (int ks = 0; ks < 8; ++ks)
    a[ks] = *(const bf16x8*)&As[(qr0 + l15) * XW + ks * 32 + l4 * 8];
  int destRow[4];
#pragma unroll
  for (int r = 0; r < 4; ++r) destRow[r] = idx[brow0 + qr0 + l4 * 4 + r];
  const int b = brow0 >> 14;
  for (int ct = 0; ct < 16; ++ct) {
    f32x4 acc = {0.f, 0.f, 0.f, 0.f};
#pragma unroll
    for (int ks = 0; ks < 8; ++ks) {
      bf16x8 bfr = *(const bf16x8*)&WpT[(ct * 16 + l15) * 256 + ks * 32 + l4 * 8];
      acc = __builtin_amdgcn_mfma_f32_16x16x32_bf16(a[ks], bfr, acc, 0, 0, 0);
    }
#pragma unroll
    for (int r = 0; r < 4; ++r)
      out[((size_t)b * N_ + destRow[r]) * DIM_ + ct * 16 + l15] = acc[r];
  }
}

extern "C" void kernel_launch(void* const* d_in, const int* in_sizes, int n_in,
                              void* d_out, int out_size, void* d_ws, size_t ws_size,
                              hipStream_t stream) {
  const float* x    = (const float*)d_in[0];
  const int*   idx  = (const int*)d_in[1];
  const float* kgf  = (const float*)d_in[2];
  const float* vgf  = (const float*)d_in[3];
  const int*   sbi  = (const int*)d_in[4];
  const float* prev = (const float*)d_in[5];
  const float* Wq   = (const float*)d_in[6];
  const float* Wk   = (const float*)d_in[7];
  const float* Wv   = (const float*)d_in[8];
  const float* Wp   = (const float*)d_in[9];
  float* out = (float*)d_out;
  float* fusedOut = out + (size_t)B_ * N_ * DIM_;

  char* ws = (char*)d_ws;
  unsigned short* WT     = (unsigned short*)ws;                 // 4 x 256x256 bf16 (WqT,WkT,WvT,WprojT)
  unsigned short* kgb    = (unsigned short*)(ws + 524288);      // [8][64][32] bf16
  unsigned short* vgt    = (unsigned short*)(ws + 557056);      // [8][32][64] bf16
  unsigned short* qg     = (unsigned short*)(ws + 589824);      // [B][H][N][32] bf16
  unsigned short* kga    = qg  + (size_t)B_ * H_ * N_ * DH_;
  unsigned short* vga    = kga + (size_t)B_ * H_ * N_ * DH_;
  unsigned short* outPre = vga + (size_t)B_ * H_ * N_ * DH_;    // [B][N][256] bf16 (gathered order)

  k0_transpose<<<dim3(8, 8, 4), 256, 0, stream>>>(Wq, Wk, Wv, Wp, WT);
  k0_kgvg<<<64, 256, 0, stream>>>(kgf, vgf, kgb, vgt);
  k1_qkv<<<256, 512, 0, stream>>>(x, idx, WT, qg, kga, vga);
  k2_attn<<<2048, 512, 0, stream>>>(qg, kga, vga, kgb, vgt, sbi, prev, fusedOut, outPre);
  k3_proj<<<256, 512, 0, stream>>>(outPre, WT + 3 * 65536, idx, out);
}

// Round 2
// 692.641 us; speedup vs baseline: 1.1632x; 1.1632x over previous
//
#include <hip/hip_runtime.h>

typedef __attribute__((ext_vector_type(8))) short bf16x8;
typedef __attribute__((ext_vector_type(8))) unsigned short u16x8;
typedef __attribute__((ext_vector_type(4))) unsigned short u16x4;
typedef __attribute__((ext_vector_type(4))) float f32x4;

#define B_ 2
#define N_ 16384
#define DIM_ 256
#define H_ 8
#define DH_ 32
#define GS_ 128
#define NG_ 128
#define M_ 64
#define SCALE 0.17677669529663687f   // 1/sqrt(32)

#define XW 264   // LDS row: 256 + 8 pad -> 528B stride (33*16)

__device__ __forceinline__ unsigned short f2bf(float x) {
  union { float f; unsigned u; } v; v.f = x;
  unsigned r = v.u + 0x7fffu + ((v.u >> 16) & 1u);
  return (unsigned short)(r >> 16);
}
__device__ __forceinline__ float bf2f(unsigned us16) {  // low 16 bits = bf16
  union { unsigned u; float f; } v; v.u = us16 << 16; return v.f;
}
__device__ __forceinline__ unsigned pack2(float a, float b) {
  return (unsigned)f2bf(a) | ((unsigned)f2bf(b) << 16);
}

// P-register -> MFMA A-fragment exchange (within wave).
// Target lane (l15,l4) builds its 8 bf16 (k = kt*32 + l4*8 + j) from
// source lanes l15+(l4&1)*32 (quads j0..3) and +16 (j4..7), register wt = 2kt + (l4>>1).
__device__ __forceinline__ bf16x8 xchg(unsigned loA, unsigned hiA, unsigned loB, unsigned hiB,
                                       int idxA, int idxB, bool hiSel) {
  unsigned a0 = (unsigned)__builtin_amdgcn_ds_bpermute(idxA, (int)loA);
  unsigned a1 = (unsigned)__builtin_amdgcn_ds_bpermute(idxA, (int)loB);
  unsigned b0 = (unsigned)__builtin_amdgcn_ds_bpermute(idxA, (int)hiA);
  unsigned b1 = (unsigned)__builtin_amdgcn_ds_bpermute(idxA, (int)hiB);
  unsigned c0 = (unsigned)__builtin_amdgcn_ds_bpermute(idxB, (int)loA);
  unsigned c1 = (unsigned)__builtin_amdgcn_ds_bpermute(idxB, (int)loB);
  unsigned d0 = (unsigned)__builtin_amdgcn_ds_bpermute(idxB, (int)hiA);
  unsigned d1 = (unsigned)__builtin_amdgcn_ds_bpermute(idxB, (int)hiB);
  union { unsigned u[4]; bf16x8 v; } U;
  U.u[0] = hiSel ? a1 : a0;
  U.u[1] = hiSel ? b1 : b0;
  U.u[2] = hiSel ? c1 : c0;
  U.u[3] = hiSel ? d1 : d0;
  return U.v;
}

// ---------------- K0a: transpose W (f32 [256][256]) -> WT (bf16 [256][256]) ----------------
__global__ void k0_transpose(const float* __restrict__ W0, const float* __restrict__ W1,
                             const float* __restrict__ W2, const float* __restrict__ W3,
                             unsigned short* __restrict__ WT) {
  __shared__ float t[32][33];
  const float* W = (blockIdx.z == 0) ? W0 : (blockIdx.z == 1) ? W1 : (blockIdx.z == 2) ? W2 : W3;
  unsigned short* D = WT + (size_t)blockIdx.z * 65536;
  int tx = threadIdx.x & 31, ty = threadIdx.x >> 5;
  int r0 = blockIdx.y * 32, c0 = blockIdx.x * 32;
#pragma unroll
  for (int k = 0; k < 4; ++k)
    t[ty + 8 * k][tx] = W[(size_t)(r0 + ty + 8 * k) * 256 + c0 + tx];
  __syncthreads();
#pragma unroll
  for (int k = 0; k < 4; ++k)
    D[(size_t)(c0 + ty + 8 * k) * 256 + r0 + tx] = f2bf(t[tx][ty + 8 * k]);
}

// ---------------- K0b: k_global -> bf16 copy; v_global -> bf16 transposed [h][d][m] --------
__global__ void k0_kgvg(const float* __restrict__ kgf, const float* __restrict__ vgf,
                        unsigned short* __restrict__ kgb, unsigned short* __restrict__ vgt) {
  int i = blockIdx.x * 256 + threadIdx.x;
  if (i < H_ * M_ * DH_) {
    kgb[i] = f2bf(kgf[i]);
    int hh = i >> 11, rem = i & 2047, d = rem >> 6, mm = rem & 63;
    vgt[i] = f2bf(vgf[((size_t)hh * M_ + mm) * DH_ + d]);
  }
}

// ---------------- K1: gathered QKV projection. q,k -> [B][H][N][32]; v -> [B][H][32][N] ----
__global__ __launch_bounds__(256) void k1_qkv(const float* __restrict__ x, const int* __restrict__ idx,
                                              const unsigned short* __restrict__ WT,
                                              unsigned short* __restrict__ qg,
                                              unsigned short* __restrict__ kg,
                                              unsigned short* __restrict__ vgt2) {
  __shared__ __attribute__((aligned(16))) unsigned short Xs[64 * XW];
  const int tid = threadIdx.x;
  const int brow0 = blockIdx.x * 64;  // gathered global row base (b*N + n)
  const int b = brow0 >> 14;
  {
    int r = tid >> 2, part = tid & 3;
    int src = idx[brow0 + r];
    const float* xp = x + ((size_t)b * N_ + src) * DIM_ + part * 64;
    unsigned short* dp = &Xs[r * XW + part * 64];
#pragma unroll
    for (int i = 0; i < 8; ++i) {
      float4 v0 = ((const float4*)xp)[2 * i];
      float4 v1 = ((const float4*)xp)[2 * i + 1];
      u16x8 o;
      o[0] = f2bf(v0.x); o[1] = f2bf(v0.y); o[2] = f2bf(v0.z); o[3] = f2bf(v0.w);
      o[4] = f2bf(v1.x); o[5] = f2bf(v1.y); o[6] = f2bf(v1.z); o[7] = f2bf(v1.w);
      *(u16x8*)(dp + i * 8) = o;
    }
  }
  __syncthreads();
  const int lane = tid & 63, wid = tid >> 6;
  const int l15 = lane & 15, l4 = lane >> 4;
  const int qr0 = wid * 16;
  bf16x8 a[8];
#pragma unroll
  for (int ks = 0; ks < 8; ++ks)
    a[ks] = *(const bf16x8*)&Xs[(qr0 + l15) * XW + ks * 32 + l4 * 8];
  const int nbase = (brow0 + qr0 + l4 * 4) & (N_ - 1);
  for (int ct = 0; ct < 16; ++ct) {
    f32x4 accq = {0.f, 0.f, 0.f, 0.f};
    f32x4 acck = {0.f, 0.f, 0.f, 0.f};
    f32x4 accv = {0.f, 0.f, 0.f, 0.f};
#pragma unroll
    for (int ks = 0; ks < 8; ++ks) {
      const unsigned short* wrow = &WT[(ct * 16 + l15) * 256 + ks * 32 + l4 * 8];
      accq = __builtin_amdgcn_mfma_f32_16x16x32_bf16(a[ks], *(const bf16x8*)wrow, accq, 0, 0, 0);
      acck = __builtin_amdgcn_mfma_f32_16x16x32_bf16(a[ks], *(const bf16x8*)(wrow + 65536), acck, 0, 0, 0);
      accv = __builtin_amdgcn_mfma_f32_16x16x32_bf16(a[ks], *(const bf16x8*)(wrow + 131072), accv, 0, 0, 0);
    }
    int col = ct * 16 + l15, hh = col >> 5, cc = col & 31;
    size_t qkbase = ((size_t)(b * H_ + hh)) * N_ * DH_ + cc;
#pragma unroll
    for (int r = 0; r < 4; ++r) {
      size_t o = qkbase + (size_t)(nbase + r) * DH_;
      qg[o] = f2bf(accq[r]);
      kg[o] = f2bf(acck[r]);
    }
    u16x4 vv;
    vv[0] = f2bf(accv[0]); vv[1] = f2bf(accv[1]); vv[2] = f2bf(accv[2]); vv[3] = f2bf(accv[3]);
    *(u16x4*)&vgt2[((size_t)(b * H_ + hh) * DH_ + cc) * N_ + nbase] = vv;
  }
}

// ---------------- K2: fused windowed + global attention, all-register swapped layout -------
__global__ __launch_bounds__(512) void k2_attn(
    const unsigned short* __restrict__ qg, const unsigned short* __restrict__ kga,
    const unsigned short* __restrict__ vgt2, const unsigned short* __restrict__ kglob,
    const unsigned short* __restrict__ vgt, const int* __restrict__ sbi,
    const float* __restrict__ prev, float* __restrict__ fusedOut,
    unsigned short* __restrict__ outPre) {
  __shared__ __attribute__((aligned(16))) int bq[128];
  __shared__ __attribute__((aligned(16))) int bk[256];

  const int tid = threadIdx.x;
  const int h = blockIdx.x & 7;
  const int g = (blockIdx.x >> 3) & 127;
  const int b = blockIdx.x >> 10;
  const int n0 = g * GS_;
  const size_t headBase = ((size_t)b * H_ + h) * (size_t)N_ * DH_;

  if (tid < 128) bq[tid] = sbi[b * N_ + n0 + tid];
  else if (tid < 384) {
    int w = tid - 128;
    int srcn = (w < 128 || g < NG_ - 1) ? (n0 + w) : (N_ - 1 - (w - 128));
    bk[w] = sbi[b * N_ + srcn];
  }
  __syncthreads();

  const int lane = tid & 63, wid = tid >> 6;
  const int l15 = lane & 15, l4 = lane >> 4;
  const int qr0 = wid * 16;
  const int q = qr0 + l15;           // this lane's query row (0..127)

  const bf16x8 qb = *(const bf16x8*)&qg[headBase + (size_t)(n0 + q) * DH_ + l4 * 8];
  const int myb = bq[q];

  // ---- window pass: S^T = K*Q^T, lane holds P[q=l15][kpos=wt*16+l4*4+r] ----
  unsigned pkl[16], pkh[16];
  unsigned long long mbits = 0ull;
  float sm = 0.f;
#pragma unroll
  for (int wt = 0; wt < 16; ++wt) {
    int w = wt * 16 + l15;
    int srcn = (w < 128 || g < NG_ - 1) ? (n0 + w) : (N_ - 1 - (w - 128));
    bf16x8 ka = *(const bf16x8*)&kga[headBase + (size_t)srcn * DH_ + l4 * 8];
    f32x4 z = {0.f, 0.f, 0.f, 0.f};
    f32x4 s = __builtin_amdgcn_mfma_f32_16x16x32_bf16(ka, qb, z, 0, 0, 0);
    int4 kb = *(const int4*)&bk[wt * 16 + l4 * 4];
    const int kbv[4] = {kb.x, kb.y, kb.z, kb.w};
    float p[4];
#pragma unroll
    for (int r = 0; r < 4; ++r) {
      bool m = (kbv[r] == myb);
      p[r] = m ? __expf(s[r] * SCALE) : 0.f;   // no max-subtraction: |logit| small, f32-safe
      sm += p[r];
      mbits |= (unsigned long long)(m ? 1 : 0) << (wt * 4 + r);
    }
    pkl[wt] = pack2(p[0], p[1]);
    pkh[wt] = pack2(p[2], p[3]);
  }

  // ---- global pass: 64 shared tokens ----
  unsigned p2l[4], p2h[4];
  float s2 = 0.f;
#pragma unroll
  for (int wt = 0; wt < 4; ++wt) {
    bf16x8 ga = *(const bf16x8*)&kglob[((size_t)h * M_ + wt * 16 + l15) * DH_ + l4 * 8];
    f32x4 z = {0.f, 0.f, 0.f, 0.f};
    f32x4 s = __builtin_amdgcn_mfma_f32_16x16x32_bf16(ga, qb, z, 0, 0, 0);
    float p[4];
#pragma unroll
    for (int r = 0; r < 4; ++r) {
      p[r] = __expf(s[r] * SCALE);
      s2 += p[r];
    }
    p2l[wt] = pack2(p[0], p[1]);
    p2h[wt] = pack2(p[2], p[3]);
  }

  sm += __shfl_xor(sm, 16); sm += __shfl_xor(sm, 32);
  s2 += __shfl_xor(s2, 16); s2 += __shfl_xor(s2, 32);
  const float halfinv = 0.5f / sm;
  const float invs2 = 1.f / s2;

  // ---- fuse with prev, accumulate fused row-sum ----
  const size_t pbase = (((size_t)(b * NG_ + g) * H_ + h) * GS_ + q) * (size_t)(2 * GS_) + l4 * 4;
  float fs = 0.f;
#pragma unroll
  for (int wt = 0; wt < 16; ++wt) {
    float4 pr = *(const float4*)&prev[pbase + wt * 16];
    const float prv[4] = {pr.x, pr.y, pr.z, pr.w};
    float p[4] = {bf2f(pkl[wt] & 0xffffu), bf2f(pkl[wt] >> 16),
                  bf2f(pkh[wt] & 0xffffu), bf2f(pkh[wt] >> 16)};
    float f[4];
#pragma unroll
    for (int r = 0; r < 4; ++r) {
      bool m = (mbits >> (wt * 4 + r)) & 1ull;
      f[r] = m ? (0.5f * prv[r] + halfinv * p[r]) : 0.f;
      fs += f[r];
    }
    pkl[wt] = pack2(f[0], f[1]);
    pkh[wt] = pack2(f[2], f[3]);
  }
  fs += __shfl_xor(fs, 16); fs += __shfl_xor(fs, 32);
  const float fn = 1.f / (fs + 1e-9f);

  // ---- write normalized fused map (float4) ----
#pragma unroll
  for (int wt = 0; wt < 16; ++wt) {
    float4 o;
    o.x = bf2f(pkl[wt] & 0xffffu) * fn;
    o.y = bf2f(pkl[wt] >> 16) * fn;
    o.z = bf2f(pkh[wt] & 0xffffu) * fn;
    o.w = bf2f(pkh[wt] >> 16) * fn;
    *(float4*)&fusedOut[pbase + wt * 16] = o;
  }

  // ---- PV: out = fn*(F @ Vwin) + invs2*(P2 @ vg), A-frags via bpermute exchange ----
  const int idxA = (l15 + (l4 & 1) * 32) * 4;
  const int idxB = idxA + 64;
  const bool hiSel = (l4 >= 2);
  f32x4 aw0 = {0.f, 0.f, 0.f, 0.f}, aw1 = {0.f, 0.f, 0.f, 0.f};
  f32x4 ag0 = {0.f, 0.f, 0.f, 0.f}, ag1 = {0.f, 0.f, 0.f, 0.f};
  const size_t vrow0 = ((size_t)(b * H_ + h) * DH_ + l15) * (size_t)N_;
  const size_t vrow1 = vrow0 + (size_t)16 * N_;
#pragma unroll
  for (int kt = 0; kt < 8; ++kt) {
    bf16x8 af = xchg(pkl[2 * kt], pkh[2 * kt], pkl[2 * kt + 1], pkh[2 * kt + 1], idxA, idxB, hiSel);
    bf16x8 bv0, bv1;
    if (g == NG_ - 1 && kt >= 4) {  // flipped tail rows: per-element gather (16 of 2048 blocks)
#pragma unroll
      for (int j = 0; j < 8; ++j) {
        int kp = kt * 32 + l4 * 8 + j;
        int sn = N_ - 1 - (kp - 128);
        bv0[j] = (short)vgt2[vrow0 + sn];
        bv1[j] = (short)vgt2[vrow1 + sn];
      }
    } else {
      bv0 = *(const bf16x8*)&vgt2[vrow0 + n0 + kt * 32 + l4 * 8];
      bv1 = *(const bf16x8*)&vgt2[vrow1 + n0 + kt * 32 + l4 * 8];
    }
    aw0 = __builtin_amdgcn_mfma_f32_16x16x32_bf16(af, bv0, aw0, 0, 0, 0);
    aw1 = __builtin_amdgcn_mfma_f32_16x16x32_bf16(af, bv1, aw1, 0, 0, 0);
  }
#pragma unroll
  for (int kt = 0; kt < 2; ++kt) {
    bf16x8 af = xchg(p2l[2 * kt], p2h[2 * kt], p2l[2 * kt + 1], p2h[2 * kt + 1], idxA, idxB, hiSel);
    bf16x8 b0 = *(const bf16x8*)&vgt[((size_t)h * DH_ + l15) * M_ + kt * 32 + l4 * 8];
    bf16x8 b1 = *(const bf16x8*)&vgt[((size_t)h * DH_ + 16 + l15) * M_ + kt * 32 + l4 * 8];
    ag0 = __builtin_amdgcn_mfma_f32_16x16x32_bf16(af, b0, ag0, 0, 0, 0);
    ag1 = __builtin_amdgcn_mfma_f32_16x16x32_bf16(af, b1, ag1, 0, 0, 0);
  }

  // ---- combine + store (C-layout rows need per-row fn/invs2 via shfl) ----
#pragma unroll
  for (int r = 0; r < 4; ++r) {
    float fnC = __shfl(fn, l4 * 4 + r);
    float iC = __shfl(invs2, l4 * 4 + r);
    int n = n0 + qr0 + l4 * 4 + r;
    size_t o = ((size_t)b * N_ + n) * DIM_ + h * DH_ + l15;
    outPre[o] = f2bf(fnC * aw0[r] + iC * ag0[r]);
    outPre[o + 16] = f2bf(fnC * aw1[r] + iC * ag1[r]);
  }
}

// ---------------- K3: out[b, idx[n], :] = outPre[b, n, :] @ Wproj ----------------
__global__ __launch_bounds__(256) void k3_proj(const unsigned short* __restrict__ outPre,
                                               const unsigned short* __restrict__ WpT,
                                               const int* __restrict__ idx,
                                               float* __restrict__ out) {
  __shared__ __attribute__((aligned(16))) unsigned short As[64 * XW];
  const int tid = threadIdx.x;
  const int brow0 = blockIdx.x * 64;
  const int b = brow0 >> 14;
  {
    int r = tid >> 2, part = tid & 3;
    const unsigned short* sp = &outPre[(size_t)(brow0 + r) * 256 + part * 64];
    unsigned short* dp = &As[r * XW + part * 64];
#pragma unroll
    for (int i = 0; i < 8; ++i)
      *(u16x8*)(dp + i * 8) = *(const u16x8*)(sp + i * 8);
  }
  __syncthreads();
  const int lane = tid & 63, wid = tid >> 6;
  const int l15 = lane & 15, l4 = lane >> 4;
  const int qr0 = wid * 16;
  bf16x8 a[8];
#pragma unroll
  for (int ks = 0; ks < 8; ++ks)
    a[ks] = *(const bf16x8*)&As[(qr0 + l15) * XW + ks * 32 + l4 * 8];
  int destRow[4];
#pragma unroll
  for (int r = 0; r < 4; ++r) destRow[r] = idx[brow0 + qr0 + l4 * 4 + r];
  for (int ct2 = 0; ct2 < 8; ++ct2) {
    f32x4 acc0 = {0.f, 0.f, 0.f, 0.f};
    f32x4 acc1 = {0.f, 0.f, 0.f, 0.f};
#pragma unroll
    for (int ks = 0; ks < 8; ++ks) {
      const unsigned short* wrow = &WpT[(ct2 * 32 + l15) * 256 + ks * 32 + l4 * 8];
      acc0 = __builtin_amdgcn_mfma_f32_16x16x32_bf16(a[ks], *(const bf16x8*)wrow, acc0, 0, 0, 0);
      acc1 = __builtin_amdgcn_mfma_f32_16x16x32_bf16(a[ks], *(const bf16x8*)(wrow + 16 * 256), acc1, 0, 0, 0);
    }
#pragma unroll
    for (int r = 0; r < 4; ++r) {
      size_t o = ((size_t)b * N_ + destRow[r]) * DIM_ + ct2 * 32 + l15;
      out[o] = acc0[r];
      out[o + 16] = acc1[r];
    }
  }
}

extern "C" void kernel_launch(void* const* d_in, const int* in_sizes, int n_in,
                              void* d_out, int out_size, void* d_ws, size_t ws_size,
                              hipStream_t stream) {
  const float* x    = (const float*)d_in[0];
  const int*   idx  = (const int*)d_in[1];
  const float* kgf  = (const float*)d_in[2];
  const float* vgf  = (const float*)d_in[3];
  const int*   sbi  = (const int*)d_in[4];
  const float* prev = (const float*)d_in[5];
  const float* Wq   = (const float*)d_in[6];
  const float* Wk   = (const float*)d_in[7];
  const float* Wv   = (const float*)d_in[8];
  const float* Wp   = (const float*)d_in[9];
  float* out = (float*)d_out;
  float* fusedOut = out + (size_t)B_ * N_ * DIM_;

  char* ws = (char*)d_ws;
  unsigned short* WT     = (unsigned short*)ws;                 // 4 x 256x256 bf16 (WqT,WkT,WvT,WprojT)
  unsigned short* kgb    = (unsigned short*)(ws + 524288);      // [8][64][32] bf16
  unsigned short* vgt    = (unsigned short*)(ws + 557056);      // [8][32][64] bf16
  unsigned short* qg     = (unsigned short*)(ws + 589824);      // [B][H][N][32] bf16
  unsigned short* kga    = qg  + (size_t)B_ * H_ * N_ * DH_;    // [B][H][N][32]
  unsigned short* vgt2   = kga + (size_t)B_ * H_ * N_ * DH_;    // [B][H][32][N] (transposed V)
  unsigned short* outPre = vgt2 + (size_t)B_ * H_ * N_ * DH_;   // [B][N][256] bf16 (gathered order)

  k0_transpose<<<dim3(8, 8, 4), 256, 0, stream>>>(Wq, Wk, Wv, Wp, WT);
  k0_kgvg<<<64, 256, 0, stream>>>(kgf, vgf, kgb, vgt);
  k1_qkv<<<512, 256, 0, stream>>>(x, idx, WT, qg, kga, vgt2);
  k2_attn<<<2048, 512, 0, stream>>>(qg, kga, vgt2, kgb, vgt, sbi, prev, fusedOut, outPre);
  k3_proj<<<512, 256, 0, stream>>>(outPre, WT + 3 * 65536, idx, out);
}